// Round 10
// baseline (172.767 us; speedup 1.0000x reference)
//
#include <hip/hip_runtime.h>

#define HIDDEN 64
#define RANGE 512    // nodes per range; one build block per range
#define RSHIFT 9
#define RB 256       // LDS range-counter array size (>= R = 196)
#define NWR 512      // writer blocks (pre grid); each owns one contiguous edge slice
#define ECMAX 3328   // max edges per writer block (LDS sort capacity)
#define RCAP 12288   // col slots per range (lambda=8163, +45 sigma)
#define OUTMAX 512   // LDS pooling bins (n_graphs)

// ---------- dispatch 1: embu + weight-chain + out-zero + per-block LDS range-sort ----------
// (round-7 proven structure; tables packed off | cnt<<16)
// pairs word = (d - r*RANGE) << 17 | s   (s < 2^17, d_off < 2^9)
__global__ __launch_bounds__(256) void pre_kernel(const float* __restrict__ emb,
                                                  const float* __restrict__ Ws,
                                                  const float* __restrict__ bs,
                                                  const float* __restrict__ Wreg,
                                                  float* __restrict__ wt,
                                                  float* __restrict__ embu, int V,
                                                  const int* __restrict__ src,
                                                  const int* __restrict__ dst,
                                                  unsigned* __restrict__ pairs,
                                                  unsigned short* __restrict__ srcb,
                                                  unsigned* __restrict__ tin,
                                                  unsigned* __restrict__ tout,
                                                  float* __restrict__ out, int out_n,
                                                  int E, int EC, int R) {
    __shared__ float u3[HIDDEN], u2[HIDDEN], u1[HIDDEN];
    __shared__ int hin[RB], hout[RB];
    __shared__ int tmp[256];
    __shared__ unsigned plds[ECMAX];
    __shared__ unsigned short slds[ECMAX];
    int t = threadIdx.x;
    int b = blockIdx.x;
    // ---- weight chain (every block; needed for embu) ----
    const float* W0 = Ws;
    const float* W1 = Ws + HIDDEN * HIDDEN;
    const float* W2 = Ws + 2 * HIDDEN * HIDDEN;
    if (t < HIDDEN) { float s = 0.f; for (int j = 0; j < HIDDEN; j++) s += W2[t*HIDDEN+j] * Wreg[j]; u3[t] = s; }
    __syncthreads();
    if (t < HIDDEN) { float s = 0.f; for (int j = 0; j < HIDDEN; j++) s += W1[t*HIDDEN+j] * u3[j]; u2[t] = s; }
    __syncthreads();
    if (t < HIDDEN) { float s = 0.f; for (int j = 0; j < HIDDEN; j++) s += W0[t*HIDDEN+j] * u2[j]; u1[t] = s; }
    __syncthreads();
    if (b == 0) {
        if (t < HIDDEN) {
            float c1v = bs[t] * u2[t];
            float c2v = bs[HIDDEN + t] * u3[t];
            float c3v = bs[2*HIDDEN + t] * Wreg[t];
#pragma unroll
            for (int off = 32; off > 0; off >>= 1) {
                c1v += __shfl_down(c1v, off, 64);
                c2v += __shfl_down(c2v, off, 64);
                c3v += __shfl_down(c3v, off, 64);
            }
            if (t == 0) { wt[64] = c1v; wt[65] = c2v; wt[66] = c3v; }
        }
        for (int i = t; i < out_n; i += 256) out[i] = 0.0f;
    }
    // ---- embu: embu[v] = emb[v] . u1, 16 rows per task ----
    int lane = t & 63, warp = t >> 6, vs = lane >> 4, ln = lane & 15;
    int EV = (V + 15) >> 4;
    for (int task = b; task < EV; task += gridDim.x) {
        int v = task * 16 + warp * 4 + vs;
        if (v < V) {
            const float* row = emb + (size_t)v * HIDDEN;
            float acc = row[ln]*u1[ln] + row[16+ln]*u1[16+ln]
                      + row[32+ln]*u1[32+ln] + row[48+ln]*u1[48+ln];
            acc += __shfl_xor(acc, 1, 64);
            acc += __shfl_xor(acc, 2, 64);
            acc += __shfl_xor(acc, 4, 64);
            acc += __shfl_xor(acc, 8, 64);
            if (ln == 0) embu[v] = acc;
        }
    }
    // ---- pass 1: range histograms for this slice ----
    for (int i = t; i < RB; i += 256) { hin[i] = 0; hout[i] = 0; }
    __syncthreads();
    int es = b * EC, ee = min(E, es + EC);
    int cntE = ee - es;
    for (int e = es + t; e < ee; e += 256) {
        atomicAdd(&hin[dst[e] >> RSHIFT], 1);
        atomicAdd(&hout[src[e] >> RSHIFT], 1);
    }
    __syncthreads();
    // ---- exclusive scans over 256 range counters; emit packed run tables ----
    int vin = hin[t], vout = hout[t];
    tmp[t] = vin;
    __syncthreads();
    for (int off = 1; off < 256; off <<= 1) {
        int u = (t >= off) ? tmp[t - off] : 0;
        __syncthreads();
        tmp[t] += u;
        __syncthreads();
    }
    int ein = tmp[t] - vin;
    tmp[t] = vout;
    __syncthreads();
    for (int off = 1; off < 256; off <<= 1) {
        int u = (t >= off) ? tmp[t - off] : 0;
        __syncthreads();
        tmp[t] += u;
        __syncthreads();
    }
    int eout = tmp[t] - vout;
    if (t < R) {
        tin [(size_t)t * NWR + b] = (unsigned)ein  | ((unsigned)vin  << 16);
        tout[(size_t)t * NWR + b] = (unsigned)eout | ((unsigned)vout << 16);
    }
    hin[t] = ein;                    // reuse as scatter cursors
    hout[t] = eout;
    __syncthreads();
    // ---- pass 2: scatter into LDS (slice re-read is L2-hot) ----
    for (int e = es + t; e < ee; e += 256) {
        int s = src[e], d = dst[e];
        int r = d >> RSHIFT;
        int lr = atomicAdd(&hin[r], 1);
        plds[lr] = ((unsigned)(d - (r << RSHIFT)) << 17) | (unsigned)s;
        int r2 = s >> RSHIFT;
        int lr2 = atomicAdd(&hout[r2], 1);
        slds[lr2] = (unsigned short)(s - (r2 << RSHIFT));
    }
    __syncthreads();
    // ---- coalesced copy-out of the sorted slice ----
    unsigned* pg = pairs + (size_t)b * EC;
    unsigned short* sg = srcb + (size_t)b * EC;
    for (int i = t; i < cntE; i += 256) pg[i] = plds[i];
    for (int i = t; i < cntE; i += 256) sg[i] = slds[i];
}

// ---------- dispatch 2 (v2): one 512-thread block per range.
// 16-lane GROUPS walk runs in parallel (coalesced ~64B per run, 4 runs in flight/wave)
// instead of one serial thread per run. 512-thread single-level scan. ----------
__global__ __launch_bounds__(512) void build_kernel(const unsigned* __restrict__ pairs,
                                                    const unsigned short* __restrict__ srcb,
                                                    const unsigned* __restrict__ tin,
                                                    const unsigned* __restrict__ tout,
                                                    const int* __restrict__ feats,
                                                    const float* __restrict__ embu,
                                                    int* __restrict__ rbeg,
                                                    int* __restrict__ rend,
                                                    int* __restrict__ col,
                                                    float* __restrict__ ndst,
                                                    float* __restrict__ nsrc,
                                                    float* __restrict__ y0,
                                                    int N, int EC) {
    __shared__ int cnt[RANGE];    // dst hist (= indeg)
    __shared__ int sc[RANGE];     // exclusive scan, then fill cursor
    __shared__ int oh[RANGE];     // src hist (= outdeg)
    __shared__ int tmp[RANGE];
    __shared__ unsigned pin[NWR], pout[NWR];
    int r = blockIdx.x, t = threadIdx.x;
    int n0 = r << RSHIFT;
    int nn = min(RANGE, N - n0);
    cnt[t] = 0; oh[t] = 0;
    pin[t]  = tin [(size_t)r * NWR + t];
    pout[t] = tout[(size_t)r * NWR + t];
    __syncthreads();
    int g = t >> 4, ln = t & 15;      // 32 groups of 16 lanes
    // hist-in: group per run
    for (int b = g; b < NWR; b += 32) {
        unsigned w = pin[b];
        const unsigned* run = pairs + (size_t)b * EC + (w & 0xffff);
        int c = (int)(w >> 16);
        for (int k = ln; k < c; k += 16) atomicAdd(&cnt[run[k] >> 17], 1);
    }
    // hist-out: group per run
    for (int b = g; b < NWR; b += 32) {
        unsigned w = pout[b];
        const unsigned short* run = srcb + (size_t)b * EC + (w & 0xffff);
        int c = (int)(w >> 16);
        for (int k = ln; k < c; k += 16) atomicAdd(&oh[run[k]], 1);
    }
    __syncthreads();
    // exclusive scan of cnt[0..512): 512-thread Hillis-Steele
    int myc = cnt[t];
    tmp[t] = myc;
    __syncthreads();
    for (int off = 1; off < 512; off <<= 1) {
        int u = (t >= off) ? tmp[t - off] : 0;
        __syncthreads();
        tmp[t] += u;
        __syncthreads();
    }
    int c_in = tmp[RANGE - 1];
    sc[t] = tmp[t] - myc;
    __syncthreads();
    // per-node outputs: row bounds, norms, y0 (one node per thread)
    int base = r * RCAP;
    if (t < nn) {
        int n = n0 + t;
        rbeg[n] = base + sc[t];
        rend[n] = base + sc[t] + myc;
        ndst[n] = rsqrtf(fmaxf((float)myc, 1.0f));
        float ns = rsqrtf(fmaxf((float)oh[t], 1.0f));
        nsrc[n] = ns;
        y0[n] = embu[feats[n]] * ns;
    }
    // zero-pad 32 slots so sspmm's speculative unroll reads are safe
    if (t < 32) col[base + c_in + t] = 0;
    __syncthreads();
    // fill col (sc reused as cursor): group per run, lane per edge
    for (int b = g; b < NWR; b += 32) {
        unsigned w = pin[b];
        const unsigned* run = pairs + (size_t)b * EC + (w & 0xffff);
        int c = (int)(w >> 16);
        for (int k = ln; k < c; k += 16) {
            unsigned wv = run[k];
            int slot = atomicAdd(&sc[wv >> 17], 1);
            col[base + slot] = (int)(wv & 0x1ffff);
        }
    }
}

// ---------- scalar SpMM, MLP=4: 2 node-groups x unroll-2 (padded-CSR variant) ----------
__global__ __launch_bounds__(256) void sspmm_kernel(const int* __restrict__ rbeg,
                                                    const int* __restrict__ rend,
                                                    const int* __restrict__ col,
                                                    const float* __restrict__ y,
                                                    const float* __restrict__ ndst,
                                                    const float* __restrict__ nsrc,
                                                    const float* __restrict__ wt, int cidx,
                                                    float* __restrict__ out,
                                                    int N, int NH) {
    int lane = threadIdx.x & 63;
    int warp = threadIdx.x >> 6;
    int ns_ = lane >> 4, ln = lane & 15;
    int nA = blockIdx.x * 16 + warp * 4 + ns_;
    int nB = nA + NH;
    int begA = 0, endA = 0, begB = 0, endB = 0;
    if (nA < NH) { begA = rbeg[nA]; endA = rend[nA]; }
    if (nB < N)  { begB = rbeg[nB]; endB = rend[nB]; }
    float accA = 0.0f, accB = 0.0f;
    int jA = begA + ln, jB = begB + ln;
#pragma unroll
    for (int it = 0; it < 2; it++) {
        int ja = jA + (it << 4), jb = jB + (it << 4);
        float va = y[col[ja]];      // safe: 32 zero-padded slots past each range
        float vb = y[col[jb]];
        accA += (ja < endA) ? va : 0.0f;
        accB += (jb < endB) ? vb : 0.0f;
    }
    for (int j = jA + 32; j < endA; j += 16) accA += y[col[j]];
    for (int j = jB + 32; j < endB; j += 16) accB += y[col[j]];
#pragma unroll
    for (int m = 1; m <= 8; m <<= 1) {
        accA += __shfl_xor(accA, m, 64);
        accB += __shfl_xor(accB, m, 64);
    }
    if (ln == 0) {
        float c = wt[cidx];
        if (nA < NH) out[nA] = (accA * ndst[nA] + c) * nsrc[nA];
        if (nB < N)  out[nB] = (accB * ndst[nB] + c) * nsrc[nB];
    }
}

// ---------- last SpMM fused with pooling: LDS graph bins, one atomic per dirty bin ----------
__global__ __launch_bounds__(256) void sspmmf_kernel(const int* __restrict__ rbeg,
                                                     const int* __restrict__ rend,
                                                     const int* __restrict__ col,
                                                     const float* __restrict__ y,
                                                     const float* __restrict__ ndst,
                                                     const float* __restrict__ wt,
                                                     const int* __restrict__ gids,
                                                     float* __restrict__ out,
                                                     int N, int NH, int out_n) {
    __shared__ float sbin[OUTMAX];
    int t = threadIdx.x;
    for (int i = t; i < out_n; i += 256) sbin[i] = 0.0f;
    __syncthreads();
    int lane = t & 63;
    int warp = t >> 6;
    int ns_ = lane >> 4, ln = lane & 15;
    int nA = blockIdx.x * 16 + warp * 4 + ns_;
    int nB = nA + NH;
    int begA = 0, endA = 0, begB = 0, endB = 0;
    if (nA < NH) { begA = rbeg[nA]; endA = rend[nA]; }
    if (nB < N)  { begB = rbeg[nB]; endB = rend[nB]; }
    float accA = 0.0f, accB = 0.0f;
    int jA = begA + ln, jB = begB + ln;
#pragma unroll
    for (int it = 0; it < 2; it++) {
        int ja = jA + (it << 4), jb = jB + (it << 4);
        float va = y[col[ja]];
        float vb = y[col[jb]];
        accA += (ja < endA) ? va : 0.0f;
        accB += (jb < endB) ? vb : 0.0f;
    }
    for (int j = jA + 32; j < endA; j += 16) accA += y[col[j]];
    for (int j = jB + 32; j < endB; j += 16) accB += y[col[j]];
#pragma unroll
    for (int m = 1; m <= 8; m <<= 1) {
        accA += __shfl_xor(accA, m, 64);
        accB += __shfl_xor(accB, m, 64);
    }
    if (ln == 0) {
        float c = wt[66];
        if (nA < NH) atomicAdd(&sbin[gids[nA]], accA * ndst[nA] + c);
        if (nB < N)  atomicAdd(&sbin[gids[nB]], accB * ndst[nB] + c);
    }
    __syncthreads();
    for (int i = t; i < out_n; i += 256) {
        float v = sbin[i];
        if (v != 0.0f) atomicAdd(&out[i], v);
    }
}

extern "C" void kernel_launch(void* const* d_in, const int* in_sizes, int n_in,
                              void* d_out, int out_size, void* d_ws, size_t ws_size,
                              hipStream_t stream) {
    const int*   feats = (const int*)d_in[0];
    const int*   src   = (const int*)d_in[1];
    const int*   dst   = (const int*)d_in[2];
    const int*   gids  = (const int*)d_in[3];
    const float* emb   = (const float*)d_in[5];
    const float* Ws    = (const float*)d_in[6];
    const float* bs    = (const float*)d_in[7];
    const float* Wreg  = (const float*)d_in[8];
    float* out = (float*)d_out;

    int N = in_sizes[0];
    int E = in_sizes[1];
    int V = in_sizes[5] / HIDDEN;
    int R = (N + RANGE - 1) / RANGE;        // 196 for N=100000 (<= RB)
    int EC = (E + NWR - 1) / NWR;           // 3125 edges per writer block (<= ECMAX)
    int NH = (N + 1) / 2;
    int GS = (NH + 15) / 16;

    char* p = (char*)d_ws;
    int*   rbeg    = (int*)p;    p += (size_t)N * 4;
    int*   rend    = (int*)p;    p += (size_t)N * 4;
    float* nsrc    = (float*)p;  p += (size_t)N * 4;
    float* ndst    = (float*)p;  p += (size_t)N * 4;
    float* wt      = (float*)p;  p += 128 * 4;
    float* embu    = (float*)p;  p += (size_t)V * 4;
    float* y0      = (float*)p;  p += (size_t)N * 4;
    float* y1      = (float*)p;  p += (size_t)N * 4;
    float* y2      = (float*)p;  p += (size_t)N * 4;
    unsigned* tin  = (unsigned*)p;  p += (size_t)R * NWR * 4;
    unsigned* tout = (unsigned*)p;  p += (size_t)R * NWR * 4;
    int*   col     = (int*)p;    p += (size_t)R * RCAP * 4;
    p = (char*)(((uintptr_t)p + 255) & ~(uintptr_t)255);
    unsigned* pairs = (unsigned*)p;            p += (size_t)NWR * EC * 4;
    unsigned short* srcb = (unsigned short*)p; p += (size_t)NWR * EC * 2;

    pre_kernel<<<NWR, 256, 0, stream>>>(emb, Ws, bs, Wreg, wt, embu, V,
                                        src, dst, pairs, srcb, tin, tout,
                                        out, out_size, E, EC, R);
    build_kernel<<<R, 512, 0, stream>>>(pairs, srcb, tin, tout,
                                        feats, embu, rbeg, rend, col, ndst, nsrc, y0, N, EC);

    // y1 = nsrc.(ndst.A y0 + c1); y2 = nsrc.(ndst.A y1 + c2); out = pool(ndst.A y2 + c3)
    sspmm_kernel<<<GS, 256, 0, stream>>>(rbeg, rend, col, y0, ndst, nsrc, wt, 64, y1, N, NH);
    sspmm_kernel<<<GS, 256, 0, stream>>>(rbeg, rend, col, y1, ndst, nsrc, wt, 65, y2, N, NH);
    sspmmf_kernel<<<GS, 256, 0, stream>>>(rbeg, rend, col, y2, ndst, wt, gids, out, N, NH, out_size);
}

// Round 11
// 166.032 us; speedup vs baseline: 1.0406x; 1.0406x over previous
//
#include <hip/hip_runtime.h>

#define HIDDEN 64
#define RANGE 512    // nodes per range; one build block per range
#define RSHIFT 9
#define RB 256       // LDS range-counter array size (>= R = 196)
#define NWR 512      // writer blocks (pre grid); each owns one contiguous edge slice
#define ECMAX 3328   // max edges per writer block (LDS sort capacity)
#define RCAP 12288   // col slots per range (lambda=8163, +45 sigma)
#define OUTMAX 512   // LDS pooling bins (n_graphs)

// ---------- dispatch 1: embu + weight-chain + out-zero + per-block LDS range-sort ----------
// (round-7 proven structure; tables packed off | cnt<<16)
// pairs word = (d - r*RANGE) << 17 | s   (s < 2^17, d_off < 2^9)
__global__ __launch_bounds__(256) void pre_kernel(const float* __restrict__ emb,
                                                  const float* __restrict__ Ws,
                                                  const float* __restrict__ bs,
                                                  const float* __restrict__ Wreg,
                                                  float* __restrict__ wt,
                                                  float* __restrict__ embu, int V,
                                                  const int* __restrict__ src,
                                                  const int* __restrict__ dst,
                                                  unsigned* __restrict__ pairs,
                                                  unsigned short* __restrict__ srcb,
                                                  unsigned* __restrict__ tin,
                                                  unsigned* __restrict__ tout,
                                                  float* __restrict__ out, int out_n,
                                                  int E, int EC, int R) {
    __shared__ float u3[HIDDEN], u2[HIDDEN], u1[HIDDEN];
    __shared__ int hin[RB], hout[RB];
    __shared__ int tmp[256];
    __shared__ unsigned plds[ECMAX];
    __shared__ unsigned short slds[ECMAX];
    int t = threadIdx.x;
    int b = blockIdx.x;
    // ---- weight chain (every block; needed for embu) ----
    const float* W0 = Ws;
    const float* W1 = Ws + HIDDEN * HIDDEN;
    const float* W2 = Ws + 2 * HIDDEN * HIDDEN;
    if (t < HIDDEN) { float s = 0.f; for (int j = 0; j < HIDDEN; j++) s += W2[t*HIDDEN+j] * Wreg[j]; u3[t] = s; }
    __syncthreads();
    if (t < HIDDEN) { float s = 0.f; for (int j = 0; j < HIDDEN; j++) s += W1[t*HIDDEN+j] * u3[j]; u2[t] = s; }
    __syncthreads();
    if (t < HIDDEN) { float s = 0.f; for (int j = 0; j < HIDDEN; j++) s += W0[t*HIDDEN+j] * u2[j]; u1[t] = s; }
    __syncthreads();
    if (b == 0) {
        if (t < HIDDEN) {
            float c1v = bs[t] * u2[t];
            float c2v = bs[HIDDEN + t] * u3[t];
            float c3v = bs[2*HIDDEN + t] * Wreg[t];
#pragma unroll
            for (int off = 32; off > 0; off >>= 1) {
                c1v += __shfl_down(c1v, off, 64);
                c2v += __shfl_down(c2v, off, 64);
                c3v += __shfl_down(c3v, off, 64);
            }
            if (t == 0) { wt[64] = c1v; wt[65] = c2v; wt[66] = c3v; }
        }
        for (int i = t; i < out_n; i += 256) out[i] = 0.0f;
    }
    // ---- embu: embu[v] = emb[v] . u1, 16 rows per task ----
    int lane = t & 63, warp = t >> 6, vs = lane >> 4, ln = lane & 15;
    int EV = (V + 15) >> 4;
    for (int task = b; task < EV; task += gridDim.x) {
        int v = task * 16 + warp * 4 + vs;
        if (v < V) {
            const float* row = emb + (size_t)v * HIDDEN;
            float acc = row[ln]*u1[ln] + row[16+ln]*u1[16+ln]
                      + row[32+ln]*u1[32+ln] + row[48+ln]*u1[48+ln];
            acc += __shfl_xor(acc, 1, 64);
            acc += __shfl_xor(acc, 2, 64);
            acc += __shfl_xor(acc, 4, 64);
            acc += __shfl_xor(acc, 8, 64);
            if (ln == 0) embu[v] = acc;
        }
    }
    // ---- pass 1: range histograms for this slice ----
    for (int i = t; i < RB; i += 256) { hin[i] = 0; hout[i] = 0; }
    __syncthreads();
    int es = b * EC, ee = min(E, es + EC);
    int cntE = ee - es;
    for (int e = es + t; e < ee; e += 256) {
        atomicAdd(&hin[dst[e] >> RSHIFT], 1);
        atomicAdd(&hout[src[e] >> RSHIFT], 1);
    }
    __syncthreads();
    // ---- exclusive scans over 256 range counters; emit packed run tables ----
    int vin = hin[t], vout = hout[t];
    tmp[t] = vin;
    __syncthreads();
    for (int off = 1; off < 256; off <<= 1) {
        int u = (t >= off) ? tmp[t - off] : 0;
        __syncthreads();
        tmp[t] += u;
        __syncthreads();
    }
    int ein = tmp[t] - vin;
    tmp[t] = vout;
    __syncthreads();
    for (int off = 1; off < 256; off <<= 1) {
        int u = (t >= off) ? tmp[t - off] : 0;
        __syncthreads();
        tmp[t] += u;
        __syncthreads();
    }
    int eout = tmp[t] - vout;
    if (t < R) {
        tin [(size_t)t * NWR + b] = (unsigned)ein  | ((unsigned)vin  << 16);
        tout[(size_t)t * NWR + b] = (unsigned)eout | ((unsigned)vout << 16);
    }
    hin[t] = ein;                    // reuse as scatter cursors
    hout[t] = eout;
    __syncthreads();
    // ---- pass 2: scatter into LDS (slice re-read is L2-hot) ----
    for (int e = es + t; e < ee; e += 256) {
        int s = src[e], d = dst[e];
        int r = d >> RSHIFT;
        int lr = atomicAdd(&hin[r], 1);
        plds[lr] = ((unsigned)(d - (r << RSHIFT)) << 17) | (unsigned)s;
        int r2 = s >> RSHIFT;
        int lr2 = atomicAdd(&hout[r2], 1);
        slds[lr2] = (unsigned short)(s - (r2 << RSHIFT));
    }
    __syncthreads();
    // ---- coalesced copy-out of the sorted slice ----
    unsigned* pg = pairs + (size_t)b * EC;
    unsigned short* sg = srcb + (size_t)b * EC;
    for (int i = t; i < cntE; i += 256) pg[i] = plds[i];
    for (int i = t; i < cntE; i += 256) sg[i] = slds[i];
}

// ---------- dispatch 2: one block per range — hist + scan + norms + y0 + col fill ----------
// (round-7 verbatim)
__global__ __launch_bounds__(256) void build_kernel(const unsigned* __restrict__ pairs,
                                                    const unsigned short* __restrict__ srcb,
                                                    const unsigned* __restrict__ tin,
                                                    const unsigned* __restrict__ tout,
                                                    const int* __restrict__ feats,
                                                    const float* __restrict__ embu,
                                                    int* __restrict__ rbeg,
                                                    int* __restrict__ rend,
                                                    int* __restrict__ col,
                                                    float* __restrict__ ndst,
                                                    float* __restrict__ nsrc,
                                                    float* __restrict__ y0,
                                                    int N, int EC) {
    __shared__ int cnt[RANGE];    // dst hist (= indeg)
    __shared__ int sc[RANGE];     // exclusive scan, then fill cursor
    __shared__ int oh[RANGE];     // src hist (= outdeg)
    __shared__ int tmp[256];
    __shared__ unsigned pin[NWR], pout[NWR];
    int r = blockIdx.x, t = threadIdx.x;
    int n0 = r << RSHIFT;
    int nn = min(RANGE, N - n0);
    for (int i = t; i < RANGE; i += 256) { cnt[i] = 0; oh[i] = 0; }
    for (int i = t; i < NWR; i += 256) {
        pin[i]  = tin [(size_t)r * NWR + i];
        pout[i] = tout[(size_t)r * NWR + i];
    }
    __syncthreads();
    // hist over this range's runs
    for (int b = t; b < NWR; b += 256) {
        unsigned w = pin[b];
        const unsigned* run = pairs + (size_t)b * EC + (w & 0xffff);
        int c = (int)(w >> 16);
        for (int k = 0; k < c; k++) atomicAdd(&cnt[run[k] >> 17], 1);
    }
    for (int b = t; b < NWR; b += 256) {
        unsigned w = pout[b];
        const unsigned short* run = srcb + (size_t)b * EC + (w & 0xffff);
        int c = (int)(w >> 16);
        for (int k = 0; k < c; k++) atomicAdd(&oh[run[k]], 1);
    }
    __syncthreads();
    // exclusive scan of cnt[0..512) (2 elems/thread + Hillis-Steele on 256 partials)
    int a0 = cnt[2 * t], a1 = cnt[2 * t + 1];
    tmp[t] = a0 + a1;
    __syncthreads();
    for (int off = 1; off < 256; off <<= 1) {
        int u = (t >= off) ? tmp[t - off] : 0;
        __syncthreads();
        tmp[t] += u;
        __syncthreads();
    }
    int c_in = tmp[255];
    int pre = (t > 0) ? tmp[t - 1] : 0;
    sc[2 * t] = pre;
    sc[2 * t + 1] = pre + a0;
    __syncthreads();
    // per-node outputs: row bounds, norms, y0
    int base = r * RCAP;
    for (int i = t; i < nn; i += 256) {
        int n = n0 + i;
        rbeg[n] = base + sc[i];
        rend[n] = base + sc[i] + cnt[i];
        ndst[n] = rsqrtf(fmaxf((float)cnt[i], 1.0f));
        float ns = rsqrtf(fmaxf((float)oh[i], 1.0f));
        nsrc[n] = ns;
        y0[n] = embu[feats[n]] * ns;
    }
    // zero-pad 32 slots so sspmm's speculative unroll reads are safe
    if (t < 32) col[base + c_in + t] = 0;
    __syncthreads();
    // fill col (sc reused as cursor); slice owned by this block only
    for (int b = t; b < NWR; b += 256) {
        unsigned w = pin[b];
        const unsigned* run = pairs + (size_t)b * EC + (w & 0xffff);
        int c = (int)(w >> 16);
        for (int k = 0; k < c; k++) {
            unsigned wv = run[k];
            int slot = atomicAdd(&sc[wv >> 17], 1);
            col[base + slot] = (int)(wv & 0x1ffff);
        }
    }
}

// ---------- scalar SpMM, MLP=4: 2 node-groups x unroll-2 (padded-CSR variant) ----------
__global__ __launch_bounds__(256) void sspmm_kernel(const int* __restrict__ rbeg,
                                                    const int* __restrict__ rend,
                                                    const int* __restrict__ col,
                                                    const float* __restrict__ y,
                                                    const float* __restrict__ ndst,
                                                    const float* __restrict__ nsrc,
                                                    const float* __restrict__ wt, int cidx,
                                                    float* __restrict__ out,
                                                    int N, int NH) {
    int lane = threadIdx.x & 63;
    int warp = threadIdx.x >> 6;
    int ns_ = lane >> 4, ln = lane & 15;
    int nA = blockIdx.x * 16 + warp * 4 + ns_;
    int nB = nA + NH;
    int begA = 0, endA = 0, begB = 0, endB = 0;
    if (nA < NH) { begA = rbeg[nA]; endA = rend[nA]; }
    if (nB < N)  { begB = rbeg[nB]; endB = rend[nB]; }
    float accA = 0.0f, accB = 0.0f;
    int jA = begA + ln, jB = begB + ln;
#pragma unroll
    for (int it = 0; it < 2; it++) {
        int ja = jA + (it << 4), jb = jB + (it << 4);
        float va = y[col[ja]];      // safe: 32 zero-padded slots past each range
        float vb = y[col[jb]];
        accA += (ja < endA) ? va : 0.0f;
        accB += (jb < endB) ? vb : 0.0f;
    }
    for (int j = jA + 32; j < endA; j += 16) accA += y[col[j]];
    for (int j = jB + 32; j < endB; j += 16) accB += y[col[j]];
#pragma unroll
    for (int m = 1; m <= 8; m <<= 1) {
        accA += __shfl_xor(accA, m, 64);
        accB += __shfl_xor(accB, m, 64);
    }
    if (ln == 0) {
        float c = wt[cidx];
        if (nA < NH) out[nA] = (accA * ndst[nA] + c) * nsrc[nA];
        if (nB < N)  out[nB] = (accB * ndst[nB] + c) * nsrc[nB];
    }
}

// ---------- last SpMM fused with pooling: LDS graph bins, one atomic per dirty bin ----------
__global__ __launch_bounds__(256) void sspmmf_kernel(const int* __restrict__ rbeg,
                                                     const int* __restrict__ rend,
                                                     const int* __restrict__ col,
                                                     const float* __restrict__ y,
                                                     const float* __restrict__ ndst,
                                                     const float* __restrict__ wt,
                                                     const int* __restrict__ gids,
                                                     float* __restrict__ out,
                                                     int N, int NH, int out_n) {
    __shared__ float sbin[OUTMAX];
    int t = threadIdx.x;
    for (int i = t; i < out_n; i += 256) sbin[i] = 0.0f;
    __syncthreads();
    int lane = t & 63;
    int warp = t >> 6;
    int ns_ = lane >> 4, ln = lane & 15;
    int nA = blockIdx.x * 16 + warp * 4 + ns_;
    int nB = nA + NH;
    int begA = 0, endA = 0, begB = 0, endB = 0;
    if (nA < NH) { begA = rbeg[nA]; endA = rend[nA]; }
    if (nB < N)  { begB = rbeg[nB]; endB = rend[nB]; }
    float accA = 0.0f, accB = 0.0f;
    int jA = begA + ln, jB = begB + ln;
#pragma unroll
    for (int it = 0; it < 2; it++) {
        int ja = jA + (it << 4), jb = jB + (it << 4);
        float va = y[col[ja]];
        float vb = y[col[jb]];
        accA += (ja < endA) ? va : 0.0f;
        accB += (jb < endB) ? vb : 0.0f;
    }
    for (int j = jA + 32; j < endA; j += 16) accA += y[col[j]];
    for (int j = jB + 32; j < endB; j += 16) accB += y[col[j]];
#pragma unroll
    for (int m = 1; m <= 8; m <<= 1) {
        accA += __shfl_xor(accA, m, 64);
        accB += __shfl_xor(accB, m, 64);
    }
    if (ln == 0) {
        float c = wt[66];
        if (nA < NH) atomicAdd(&sbin[gids[nA]], accA * ndst[nA] + c);
        if (nB < N)  atomicAdd(&sbin[gids[nB]], accB * ndst[nB] + c);
    }
    __syncthreads();
    for (int i = t; i < out_n; i += 256) {
        float v = sbin[i];
        if (v != 0.0f) atomicAdd(&out[i], v);
    }
}

extern "C" void kernel_launch(void* const* d_in, const int* in_sizes, int n_in,
                              void* d_out, int out_size, void* d_ws, size_t ws_size,
                              hipStream_t stream) {
    const int*   feats = (const int*)d_in[0];
    const int*   src   = (const int*)d_in[1];
    const int*   dst   = (const int*)d_in[2];
    const int*   gids  = (const int*)d_in[3];
    const float* emb   = (const float*)d_in[5];
    const float* Ws    = (const float*)d_in[6];
    const float* bs    = (const float*)d_in[7];
    const float* Wreg  = (const float*)d_in[8];
    float* out = (float*)d_out;

    int N = in_sizes[0];
    int E = in_sizes[1];
    int V = in_sizes[5] / HIDDEN;
    int R = (N + RANGE - 1) / RANGE;        // 196 for N=100000 (<= RB)
    int EC = (E + NWR - 1) / NWR;           // 3125 edges per writer block (<= ECMAX)
    int NH = (N + 1) / 2;
    int GS = (NH + 15) / 16;

    char* p = (char*)d_ws;
    int*   rbeg    = (int*)p;    p += (size_t)N * 4;
    int*   rend    = (int*)p;    p += (size_t)N * 4;
    float* nsrc    = (float*)p;  p += (size_t)N * 4;
    float* ndst    = (float*)p;  p += (size_t)N * 4;
    float* wt      = (float*)p;  p += 128 * 4;
    float* embu    = (float*)p;  p += (size_t)V * 4;
    float* y0      = (float*)p;  p += (size_t)N * 4;
    float* y1      = (float*)p;  p += (size_t)N * 4;
    float* y2      = (float*)p;  p += (size_t)N * 4;
    unsigned* tin  = (unsigned*)p;  p += (size_t)R * NWR * 4;
    unsigned* tout = (unsigned*)p;  p += (size_t)R * NWR * 4;
    int*   col     = (int*)p;    p += (size_t)R * RCAP * 4;
    p = (char*)(((uintptr_t)p + 255) & ~(uintptr_t)255);
    unsigned* pairs = (unsigned*)p;            p += (size_t)NWR * EC * 4;
    unsigned short* srcb = (unsigned short*)p; p += (size_t)NWR * EC * 2;

    pre_kernel<<<NWR, 256, 0, stream>>>(emb, Ws, bs, Wreg, wt, embu, V,
                                        src, dst, pairs, srcb, tin, tout,
                                        out, out_size, E, EC, R);
    build_kernel<<<R, 256, 0, stream>>>(pairs, srcb, tin, tout,
                                        feats, embu, rbeg, rend, col, ndst, nsrc, y0, N, EC);

    // y1 = nsrc.(ndst.A y0 + c1); y2 = nsrc.(ndst.A y1 + c2); out = pool(ndst.A y2 + c3)
    sspmm_kernel<<<GS, 256, 0, stream>>>(rbeg, rend, col, y0, ndst, nsrc, wt, 64, y1, N, NH);
    sspmm_kernel<<<GS, 256, 0, stream>>>(rbeg, rend, col, y1, ndst, nsrc, wt, 65, y2, N, NH);
    sspmmf_kernel<<<GS, 256, 0, stream>>>(rbeg, rend, col, y2, ndst, wt, gids, out, N, NH, out_size);
}